// Round 4
// baseline (295.710 us; speedup 1.0000x reference)
//
#include <hip/hip_runtime.h>

// Fused avg-pool(6x6,s4,SAME) + "unaverage" bilinear upsample.
// input (8,256,256,64) fp32 NHWC -> output (8,256,256,64) fp32.
// One block = one 32(h) x 16(w) output tile of one batch image.
// R4 changes vs R3:
//  - removed __builtin_nontemporal_store (nt defeated write-combining:
//    WRITE_SIZE was 1.87x output)
//  - XCD-aware block swizzle: b = bid & 7 puts each image on one XCD so
//    tile halos hit that XCD's L2 (FETCH was 1.9x input without it)

#define B_  8
#define H_  256
#define W_  256
#define C_  64
#define HP  64
#define WP  64
#define TH  32
#define TW  16
#define PRN 10   // pooled rows per tile
#define PCN 6    // pooled cols per tile

typedef float f4v __attribute__((ext_vector_type(4)));

// dest_to_source with s=4, dsi=2, max_src=63: lo=5.5, hi=249.5
__device__ __forceinline__ float d2s(float dest) {
    const float s = 4.0f, dsi = 2.0f, maxs = 63.0f;
    float lo = dsi + s - 0.5f;                       // 5.5
    float hi = dsi + (maxs - 1.0f) * s - 0.5f;       // 249.5
    float va = (dest - dsi) / (s - 0.5f);
    float vb = (dest - dsi + 0.5f - (maxs - 1.0f) * s) / (s - 0.5f) + maxs - 1.0f;
    float vc = (dest - dsi + 0.5f) / s;
    return dest < lo ? va : (dest > hi ? vb : vc);
}

__global__ __launch_bounds__(256, 4) void fused_kernel(const float* __restrict__ in,
                                                       float* __restrict__ out) {
    __shared__ float4 plds[PRN * PCN * 16];

    int bid = blockIdx.x;
    // XCD swizzle: blocks round-robin over 8 XCDs by bid&7 -> pin image b
    // to XCD b; remaining bits raster (ty,tx) within the image so one
    // XCD's 32 CUs sweep ~2 tile-rows (stripe ~2.75 MB, fits 4 MB L2).
    int b   = bid & 7;
    int rem = bid >> 3;
    int tx  = rem & 15;           // W_/TW = 16 tiles
    int ty  = rem >> 4;           // H_/TH = 8 tiles
    int t   = threadIdx.x;

    int PR0 = ty * (TH / 4) - 1;  // pooled row of LDS slot 0 (may be -1)
    int PC0 = tx * (TW / 4) - 1;  // pooled col of LDS slot 0 (may be -1)

    const float* bbase = in + (size_t)b * (H_ * W_ * C_);

    // ---------------- Phase A: pooled patch into LDS ----------------
    #pragma unroll
    for (int k = 0; k < 4; ++k) {
        int task = k * 256 + t;                // PRN*PCN*16 = 960 tasks
        if (task < PRN * PCN * 16) {
            int cg   = task & 15;
            int pq   = task >> 4;
            int pr_l = pq / PCN;
            int pc_l = pq - pr_l * PCN;
            int pr = PR0 + pr_l;
            int pc = PC0 + pc_l;
            int rs = 4 * pr - 1;
            int cs = 4 * pc - 1;
            float4 sum = make_float4(0.f, 0.f, 0.f, 0.f);
            #pragma unroll
            for (int dr = 0; dr < 6; ++dr) {
                int r = rs + dr;
                bool rok = (unsigned)r < (unsigned)H_;
                int rc = r < 0 ? 0 : (r > H_ - 1 ? H_ - 1 : r);
                const float4* rowp = (const float4*)(bbase + (size_t)rc * (W_ * C_));
                #pragma unroll
                for (int dc = 0; dc < 6; ++dc) {
                    int c = cs + dc;
                    bool cok = (unsigned)c < (unsigned)W_;
                    int cc = c < 0 ? 0 : (c > W_ - 1 ? W_ - 1 : c);
                    float4 v = rowp[cc * 16 + cg];
                    float w = (rok && cok) ? 1.0f : 0.0f;
                    sum.x = fmaf(v.x, w, sum.x);
                    sum.y = fmaf(v.y, w, sum.y);
                    sum.z = fmaf(v.z, w, sum.z);
                    sum.w = fmaf(v.w, w, sum.w);
                }
            }
            int rlo = rs < 0 ? 0 : rs, rhi = rs + 6 > H_ ? H_ : rs + 6;
            int clo = cs < 0 ? 0 : cs, chi = cs + 6 > W_ ? W_ : cs + 6;
            bool pok = ((unsigned)pr < (unsigned)HP) && ((unsigned)pc < (unsigned)WP);
            float scale = pok ? 1.0f / (float)((rhi - rlo) * (chi - clo)) : 0.0f;
            sum.x *= scale; sum.y *= scale; sum.z *= scale; sum.w *= scale;
            plds[(pr_l * PCN + pc_l) * 16 + cg] = sum;
        }
    }
    __syncthreads();

    // ---------------- Phase B: bilinear upsample from LDS ----------------
    int cg = t & 15;
    int wl = t >> 4;
    int wd = tx * TW + wl;
    float sc = d2s((float)wd);
    float c0f = floorf(sc);
    int c0l = (int)c0f - PC0;       // in [0, PCN-2]
    float fc = sc - c0f;

    f4v* outv = (f4v*)out;

    for (int hd_l = 0; hd_l < TH; ++hd_l) {
        int hd = ty * TH + hd_l;
        float sr = d2s((float)hd);
        float r0f = floorf(sr);
        int r0l = (int)r0f - PR0;   // in [0, PRN-2]
        float fr = sr - r0f;

        const float4* base0 = &plds[(r0l * PCN + c0l) * 16 + cg];
        float4 p00 = base0[0];
        float4 p01 = base0[16];
        float4 p10 = base0[PCN * 16];
        float4 p11 = base0[PCN * 16 + 16];

        float w00 = (1.0f - fr) * (1.0f - fc);
        float w01 = (1.0f - fr) * fc;
        float w10 = fr * (1.0f - fc);
        float w11 = fr * fc;

        f4v v;
        v.x = p00.x * w00 + p01.x * w01 + p10.x * w10 + p11.x * w11;
        v.y = p00.y * w00 + p01.y * w01 + p10.y * w10 + p11.y * w11;
        v.z = p00.z * w00 + p01.z * w01 + p10.z * w10 + p11.z * w11;
        v.w = p00.w * w00 + p01.w * w01 + p10.w * w10 + p11.w * w11;

        outv[(((size_t)b * H_ + hd) * W_ + wd) * 16 + cg] = v;
    }
}

extern "C" void kernel_launch(void* const* d_in, const int* in_sizes, int n_in,
                              void* d_out, int out_size, void* d_ws, size_t ws_size,
                              hipStream_t stream) {
    const float* in = (const float*)d_in[0];
    float* out      = (float*)d_out;
    // 8 b x 8 ty x 16 tx = 1024 blocks, 256 threads (4 blocks/CU, 16 waves/CU)
    fused_kernel<<<dim3(B_ * (H_ / TH) * (W_ / TW)), dim3(256), 0, stream>>>(in, out);
}

// Round 5
// 265.539 us; speedup vs baseline: 1.1136x; 1.1136x over previous
//
#include <hip/hip_runtime.h>

// Two-kernel version (fused R3/R4 was a net loss: 2.13x halo refetch +
// 2x write amplification -> 143 us vs ~100 us for R1's two kernels).
// input  (8,256,256,64) fp32 NHWC
// pooled (8, 64, 64,64) fp32 in d_ws (8 MiB, L2/L3-resident for kernel 2)
// output (8,256,256,64) fp32
// POOL=6 STRIDE=4 SAME -> pad_lo=1; window rows [4i-1, 4i+5).

#define B_  8
#define H_  256
#define W_  256
#define C_  64
#define HP  64
#define WP  64

typedef float f4v __attribute__((ext_vector_type(4)));

// ---------------- Kernel 1: 6x6 stride-4 SAME avg pool ----------------
// Block = one (b, pooled row i). Thread (jg,cg) makes 4 pooled pixels
// j=4jg..4jg+3 for channel-group cg: reads 6 rows x 18 cols (shared
// across the 4 windows; 108 loads vs 144 independent), branch-free
// clamp+{0,1}-mask for edges.
__global__ __launch_bounds__(256) void pool_kernel(const float* __restrict__ in,
                                                   float* __restrict__ pooled) {
    int t  = threadIdx.x;
    int cg = t & 15;          // float4 channel group
    int jg = t >> 4;          // 0..15 -> pooled cols 4jg..4jg+3
    int i  = blockIdx.x & 63; // pooled row
    int b  = blockIdx.x >> 6;

    int rs    = 4 * i - 1;    // window row start (may be -1)
    int cbase = 16 * jg - 1;  // first input col needed by window j=4jg

    const f4v* bbase = (const f4v*)in + ((size_t)b * H_ * W_ * 16) + cg;

    f4v acc0 = 0.f, acc1 = 0.f, acc2 = 0.f, acc3 = 0.f;

    #pragma unroll
    for (int dr = 0; dr < 6; ++dr) {
        int r = rs + dr;
        bool rok = (unsigned)r < (unsigned)H_;
        int rc = r < 0 ? 0 : (r > H_ - 1 ? H_ - 1 : r);
        const f4v* rowp = bbase + (size_t)rc * (W_ * 16);
        #pragma unroll
        for (int dc = 0; dc < 18; ++dc) {
            int c = cbase + dc;
            bool cok = (unsigned)c < (unsigned)W_;
            int cc = c < 0 ? 0 : (c > W_ - 1 ? W_ - 1 : c);
            f4v v = rowp[cc * 16];
            f4v vw = (rok && cok) ? v : (f4v)0.f;
            // window k covers local cols [4k, 4k+6)
            if (dc < 6)             acc0 += vw;
            if (dc >= 4 && dc < 10) acc1 += vw;
            if (dc >= 8 && dc < 14) acc2 += vw;
            if (dc >= 12)           acc3 += vw;
        }
    }

    int rlo = rs < 0 ? 0 : rs;
    int rhi = rs + 6 > H_ ? H_ : rs + 6;
    float rcnt = (float)(rhi - rlo);

    f4v accs[4] = {acc0, acc1, acc2, acc3};
    f4v* poolv = (f4v*)pooled;
    #pragma unroll
    for (int k = 0; k < 4; ++k) {
        int j = 4 * jg + k;
        int cs = 4 * j - 1;
        int clo = cs < 0 ? 0 : cs;
        int chi = cs + 6 > W_ ? W_ : cs + 6;
        float scale = 1.0f / (rcnt * (float)(chi - clo));
        poolv[(((size_t)b * HP + i) * WP + j) * 16 + cg] = accs[k] * scale;
    }
}

// ---------------- Kernel 2: "unaverage pool" bilinear upsample ----------------
// dest_to_source with s=4, dsi=2, max_src=63: lo=5.5, hi=249.5
__device__ __forceinline__ float d2s(float dest) {
    const float s = 4.0f, dsi = 2.0f, maxs = 63.0f;
    float lo = dsi + s - 0.5f;                       // 5.5
    float hi = dsi + (maxs - 1.0f) * s - 0.5f;       // 249.5
    float va = (dest - dsi) / (s - 0.5f);
    float vb = (dest - dsi + 0.5f - (maxs - 1.0f) * s) / (s - 0.5f) + maxs - 1.0f;
    float vc = (dest - dsi + 0.5f) / s;
    return dest < lo ? va : (dest > hi ? vb : vc);
}

__global__ __launch_bounds__(256) void upsample_kernel(const float* __restrict__ pooled,
                                                       float* __restrict__ out) {
    int gid = blockIdx.x * blockDim.x + threadIdx.x;
    int cg = gid & 15;
    int wd = (gid >> 4) & (W_ - 1);
    int hd = (gid >> 12) & (H_ - 1);
    int b  = gid >> 20;

    float sr = d2s((float)hd);
    float sc = d2s((float)wd);
    float r0f = floorf(sr), c0f = floorf(sc);
    int r0 = (int)r0f, c0 = (int)c0f;
    float fr = sr - r0f;
    float fc = sc - c0f;

    const f4v* pb = (const f4v*)pooled + ((size_t)b * HP * WP * 16) + cg;

    f4v p00 = 0.f, p01 = 0.f, p10 = 0.f, p11 = 0.f;
    bool rv0 = (unsigned)r0 < (unsigned)HP;
    bool rv1 = (unsigned)(r0 + 1) < (unsigned)HP;
    bool cv0 = (unsigned)c0 < (unsigned)WP;
    bool cv1 = (unsigned)(c0 + 1) < (unsigned)WP;
    if (rv0 & cv0) p00 = pb[((size_t)r0 * WP + c0) * 16];
    if (rv0 & cv1) p01 = pb[((size_t)r0 * WP + (c0 + 1)) * 16];
    if (rv1 & cv0) p10 = pb[((size_t)(r0 + 1) * WP + c0) * 16];
    if (rv1 & cv1) p11 = pb[((size_t)(r0 + 1) * WP + (c0 + 1)) * 16];

    float w00 = (1.0f - fr) * (1.0f - fc);
    float w01 = (1.0f - fr) * fc;
    float w10 = fr * (1.0f - fc);
    float w11 = fr * fc;

    f4v v = p00 * w00 + p01 * w01 + p10 * w10 + p11 * w11;
    ((f4v*)out)[gid] = v;
}

extern "C" void kernel_launch(void* const* d_in, const int* in_sizes, int n_in,
                              void* d_out, int out_size, void* d_ws, size_t ws_size,
                              hipStream_t stream) {
    const float* in  = (const float*)d_in[0];
    float* out       = (float*)d_out;
    float* pooled    = (float*)d_ws;   // 8 MiB

    // Kernel 1: block = (b, i): 8*64 = 512 blocks x 256 threads
    pool_kernel<<<dim3(B_ * HP), dim3(256), 0, stream>>>(in, pooled);
    // Kernel 2: 8*256*256*16 threads -> 32768 blocks
    upsample_kernel<<<dim3(B_ * H_ * W_ * 16 / 256), dim3(256), 0, stream>>>(pooled, out);
}